// Round 5
// baseline (334.500 us; speedup 1.0000x reference)
//
#include <hip/hip_runtime.h>
#include <hip/hip_bf16.h>
#include <math.h>

#define STU_NUM   100000
#define PROB_NUM  20000
#define KNOW_NUM  128
#define DIM       128
#define BATCH     8192
#define HIDDEN    512

// Instrumentation: repeat phases 1-5 (weight-stream + MFMA pipeline) REP times.
// Output is recomputed identically each rep (deterministic). Purpose: make the
// fused kernel the top rocprof dispatch (counters become visible) and solve
// T(ph1-5) = (dur_R5 - dur_R4) / (REP-1).
#define REP 10

typedef __attribute__((ext_vector_type(4))) float  f32x4;
typedef __attribute__((ext_vector_type(8))) __bf16 bf16x8;

__device__ __forceinline__ float sigmoidf_(float x) { return 1.0f / (1.0f + __expf(-x)); }
__device__ __forceinline__ float tanh_fast(float x) { return 1.0f - 2.0f / (__expf(2.0f * x) + 1.0f); }

// Byte offset of element (row, kk) inside a [32][64] bf16 LDS tile (4KB),
// 16B-chunk XOR swizzle to break the row-stride-128B bank alignment (T2).
__device__ __forceinline__ int swz(int row, int kk) {
    return row * 128 + ((((kk >> 3) ^ (row & 7)) << 4) | ((kk & 7) << 1));
}
// Activation buffers are arrays of [32][64] tiles along K: tile = kk>>6.
__device__ __forceinline__ bf16x8 rfragK(const char* buf, int row, int kk) {
    return *reinterpret_cast<const bf16x8*>(buf + (kk >> 6) * 4096 + swz(row, kk & 63));
}
__device__ __forceinline__ void wput(char* buf, int row, int col, float v) {
    *reinterpret_cast<__bf16*>(buf + (col >> 6) * 4096 + swz(row, col & 63)) = (__bf16)v;
}
__device__ __forceinline__ f32x4 mfma16(bf16x8 a, bf16x8 b, f32x4 c) {
    return __builtin_amdgcn_mfma_f32_16x16x32_bf16(a, b, c, 0, 0, 0);
}

// ---------------------------------------------------------------------------
// One MLP layer, barrier-free k-loop (identical to round 4).
// ---------------------------------------------------------------------------
template<int N, int K>
__device__ __forceinline__ void layerG(const __bf16* __restrict__ WT,
                                       const float* __restrict__ bias,
                                       const char* __restrict__ A, char* __restrict__ O,
                                       int wid, int lane) {
    constexpr int CG = N / 128;
    const int l15 = lane & 15, lk = (lane >> 4) * 8;
    const int nb = wid * (N / 8);
    f32x4 acc[2][CG];
    #pragma unroll
    for (int i = 0; i < 2; ++i)
        #pragma unroll
        for (int c = 0; c < CG; ++c) acc[i][c] = (f32x4){0.f, 0.f, 0.f, 0.f};

    #pragma unroll
    for (int kt = 0; kt < K / 32; ++kt) {
        const int kk = kt * 32 + lk;
        bf16x8 a0 = rfragK(A, l15, kk);
        bf16x8 a1 = rfragK(A, 16 + l15, kk);
        #pragma unroll
        for (int c = 0; c < CG; ++c) {
            bf16x8 b = *reinterpret_cast<const bf16x8*>(WT + (size_t)(nb + c * 16 + l15) * K + kk);
            acc[0][c] = mfma16(a0, b, acc[0][c]);
            acc[1][c] = mfma16(a1, b, acc[1][c]);
        }
    }
    #pragma unroll
    for (int c = 0; c < CG; ++c) {
        const int col = nb + c * 16 + l15;
        const float bv = bias[col];
        #pragma unroll
        for (int i = 0; i < 2; ++i)
            #pragma unroll
            for (int r = 0; r < 4; ++r)
                wput(O, i * 16 + (lane >> 4) * 4 + r, col, tanh_fast(acc[i][c][r] + bv));
    }
}

// ---------------------------------------------------------------------------
// Fused kernel, identical to round 4 except phases 1-5 run REP times.
// ---------------------------------------------------------------------------
__global__ __launch_bounds__(512) void fused_kernel(
    const float* __restrict__ z, const int* __restrict__ sid, const int* __restrict__ eid,
    const float* __restrict__ kp, const float* __restrict__ bstat, const float* __restrict__ bkdiff,
    const float* __restrict__ w_stat, const float* __restrict__ w_kdiff,
    const __bf16* __restrict__ KB, const __bf16* __restrict__ W1T,
    const __bf16* __restrict__ W2T, const __bf16* __restrict__ W3T,
    const float* __restrict__ b1, const float* __restrict__ b2, const float* __restrict__ b3,
    const float* __restrict__ W4, const float* __restrict__ b4,
    float* __restrict__ out) {
    __shared__ char lds[81920];
    char* Xs = lds;
    char* Xk = lds + 8192;
    char* st = lds + 16384;
    char* h1 = lds + 24576;
    char* h2 = lds + 57344;
    char* h3 = lds + 73728;

    const int t = threadIdx.x, lane = t & 63, wid = t >> 6;
    const int l15 = lane & 15, lk = (lane >> 4) * 8;
    const int rb0 = blockIdx.x * 32;
    const int colb = wid * 16 + l15;

    // ---- phase 0 (outside REP): gather Xs/Xk; prefetch KB b-frags + kp ----
    {
        int gr = t >> 3, row = gr & 31;
        bool ise = gr >= 32;
        int zrow = ise ? eid[rb0 + row] : sid[rb0 + row];
        const float* w = ise ? w_kdiff : w_stat;
        char* Xb = ise ? Xk : Xs;
        int c0 = (t & 7) * 16;
        const float4* zp = reinterpret_cast<const float4*>(z + (size_t)zrow * DIM + c0);
        const float4* wp = reinterpret_cast<const float4*>(w + c0);
        #pragma unroll
        for (int q = 0; q < 2; ++q) {
            float4 za = zp[2 * q], zb = zp[2 * q + 1];
            float4 wa = wp[2 * q], wb = wp[2 * q + 1];
            bf16x8 o;
            o[0] = (__bf16)(za.x * wa.x);  o[1] = (__bf16)(za.y * wa.y);
            o[2] = (__bf16)(za.z * wa.z);  o[3] = (__bf16)(za.w * wa.w);
            o[4] = (__bf16)(zb.x * wb.x);  o[5] = (__bf16)(zb.y * wb.y);
            o[6] = (__bf16)(zb.z * wb.z);  o[7] = (__bf16)(zb.w * wb.w);
            int c = c0 + q * 8;
            *reinterpret_cast<bf16x8*>(Xb + (c >> 6) * 4096 + swz(row, c & 63)) = o;
        }
    }
    bf16x8 kbf[4];
    #pragma unroll
    for (int kt = 0; kt < 4; ++kt)
        kbf[kt] = *reinterpret_cast<const bf16x8*>(KB + (size_t)colb * DIM + kt * 32 + lk);
    float kpv[2][4];
    #pragma unroll
    for (int i = 0; i < 2; ++i)
        #pragma unroll
        for (int r = 0; r < 4; ++r)
            kpv[i][r] = kp[(size_t)(rb0 + i * 16 + (lane >> 4) * 4 + r) * KNOW_NUM + colb];
    __syncthreads();

    // ---- phases 1-5, repeated REP times (identical work each rep) ----
    #pragma unroll 1
    for (int rep = 0; rep < REP; ++rep) {
        // phase 1: dual GEMM + sigmoid-diff -> state
        {
            f32x4 aS[2], aK[2];
            #pragma unroll
            for (int i = 0; i < 2; ++i) { aS[i] = (f32x4){0,0,0,0}; aK[i] = (f32x4){0,0,0,0}; }
            #pragma unroll
            for (int kt = 0; kt < 4; ++kt) {
                const int kk = kt * 32 + lk;
                bf16x8 s0 = rfragK(Xs, l15, kk), s1 = rfragK(Xs, 16 + l15, kk);
                bf16x8 q0 = rfragK(Xk, l15, kk), q1 = rfragK(Xk, 16 + l15, kk);
                aS[0] = mfma16(s0, kbf[kt], aS[0]);
                aS[1] = mfma16(s1, kbf[kt], aS[1]);
                aK[0] = mfma16(q0, kbf[kt], aK[0]);
                aK[1] = mfma16(q1, kbf[kt], aK[1]);
            }
            const float bs = bstat[0], bk = bkdiff[0];
            #pragma unroll
            for (int i = 0; i < 2; ++i)
                #pragma unroll
                for (int r = 0; r < 4; ++r) {
                    float v = kpv[i][r] * (sigmoidf_(aS[i][r] + bs) - sigmoidf_(aK[i][r] + bk));
                    wput(st, i * 16 + (lane >> 4) * 4 + r, colb, v);
                }
        }
        __syncthreads();

        // phases 2-4: MLP layers
        layerG<HIDDEN,     DIM>       (W1T, b1, st, h1, wid, lane);
        __syncthreads();
        layerG<HIDDEN / 2, HIDDEN>    (W2T, b2, h1, h2, wid, lane);
        __syncthreads();
        layerG<HIDDEN / 4, HIDDEN / 2>(W3T, b3, h2, h3, wid, lane);
        __syncthreads();

        // phase 5: final dot
        {
            int row  = t >> 4;
            int part = (t & 15) * 8;
            bf16x8 h = rfragK(h3, row, part);
            float s = 0.f;
            #pragma unroll
            for (int j = 0; j < 8; ++j) s += (float)h[j] * W4[part + j];
            s += __shfl_xor(s, 1); s += __shfl_xor(s, 2);
            s += __shfl_xor(s, 4); s += __shfl_xor(s, 8);
            if ((t & 15) == 0) out[rb0 + row] = sigmoidf_(s + b4[0]);
        }
        __syncthreads();
    }
}

// ---------------------------------------------------------------------------
// prep: f32 -> bf16 weight reorg (identical to round 4).
// ---------------------------------------------------------------------------
__global__ void prep_kernel(const float* __restrict__ z,
                            const float* __restrict__ W1, const float* __restrict__ W2,
                            const float* __restrict__ W3,
                            __bf16* __restrict__ KB, __bf16* __restrict__ W1T,
                            __bf16* __restrict__ W2T, __bf16* __restrict__ W3T) {
    int i = blockIdx.x * 256 + threadIdx.x;
    if (i < 16384) { KB[i] = (__bf16)z[(size_t)(STU_NUM + PROB_NUM) * DIM + i]; return; }
    i -= 16384;
    if (i < 65536) {
        int n = i >> 7, k = i & 127;
        W1T[i] = (__bf16)W1[(size_t)k * HIDDEN + n]; return;
    }
    i -= 65536;
    if (i < 131072) {
        int n = i >> 9, k = i & 511;
        W2T[i] = (__bf16)W2[(size_t)k * (HIDDEN / 2) + n]; return;
    }
    i -= 131072;
    if (i < 32768) {
        int n = i >> 8, k = i & 255;
        W3T[i] = (__bf16)W3[(size_t)k * (HIDDEN / 4) + n];
    }
}

extern "C" void kernel_launch(void* const* d_in, const int* in_sizes, int n_in,
                              void* d_out, int out_size, void* d_ws, size_t ws_size,
                              hipStream_t stream) {
    const float* z       = (const float*)d_in[0];
    const int*   sid     = (const int*)d_in[1];
    const int*   eid     = (const int*)d_in[2];
    const float* kp      = (const float*)d_in[3];
    const float* w_stat  = (const float*)d_in[4];
    const float* b_stat  = (const float*)d_in[5];
    const float* w_kdiff = (const float*)d_in[6];
    const float* b_kdiff = (const float*)d_in[7];
    const float* W1      = (const float*)d_in[8];
    const float* b1      = (const float*)d_in[9];
    const float* W2      = (const float*)d_in[10];
    const float* b2      = (const float*)d_in[11];
    const float* W3      = (const float*)d_in[12];
    const float* b3      = (const float*)d_in[13];
    const float* W4      = (const float*)d_in[14];
    const float* b4      = (const float*)d_in[15];
    float* out = (float*)d_out;

    char* ws = (char*)d_ws;
    __bf16* KB  = (__bf16*)(ws + 0);
    __bf16* W1T = (__bf16*)(ws + 32768);
    __bf16* W2T = (__bf16*)(ws + 163840);
    __bf16* W3T = (__bf16*)(ws + 425984);

    hipLaunchKernelGGL(prep_kernel, dim3(960), dim3(256), 0, stream,
                       z, W1, W2, W3, KB, W1T, W2T, W3T);

    hipLaunchKernelGGL(fused_kernel, dim3(BATCH / 32), dim3(512), 0, stream,
                       z, sid, eid, kp, b_stat, b_kdiff, w_stat, w_kdiff,
                       KB, W1T, W2T, W3T, b1, b2, b3, W4, b4, out);
}

// Round 6
// 32.631 us; speedup vs baseline: 10.2511x; 10.2511x over previous
//
#include <hip/hip_runtime.h>
#include <hip/hip_bf16.h>
#include <math.h>

#define STU_NUM   100000
#define PROB_NUM  20000
#define KNOW_NUM  128
#define DIM       128
#define BATCH     8192
#define HIDDEN    512

typedef __attribute__((ext_vector_type(4))) float  f32x4;
typedef __attribute__((ext_vector_type(8))) __bf16 bf16x8;

__device__ __forceinline__ float sigmoidf_(float x) { return 1.0f / (1.0f + __expf(-x)); }
__device__ __forceinline__ float tanh_fast(float x) { return 1.0f - 2.0f / (__expf(2.0f * x) + 1.0f); }

// Byte offset of element (row, kk) inside a [32][64] bf16 LDS tile (4KB),
// 16B-chunk XOR swizzle to break the row-stride-128B bank alignment (T2).
__device__ __forceinline__ int swz(int row, int kk) {
    return row * 128 + ((((kk >> 3) ^ (row & 7)) << 4) | ((kk & 7) << 1));
}
// Activation buffers are arrays of [32][64] tiles along K: tile = kk>>6.
__device__ __forceinline__ bf16x8 rfragK(const char* buf, int row, int kk) {
    return *reinterpret_cast<const bf16x8*>(buf + (kk >> 6) * 4096 + swz(row, kk & 63));
}
__device__ __forceinline__ void wput(char* buf, int row, int col, float v) {
    *reinterpret_cast<__bf16*>(buf + (col >> 6) * 4096 + swz(row, col & 63)) = (__bf16)v;
}
__device__ __forceinline__ f32x4 mfma16(bf16x8 a, bf16x8 b, f32x4 c) {
    return __builtin_amdgcn_mfma_f32_16x16x32_bf16(a, b, c, 0, 0, 0);
}

// ---------------------------------------------------------------------------
// MLP layer, 16-way column split (no weight-read duplication): wave wid owns
// cols [wid*N/16, (wid+1)*N/16), covers all 32 rows via two a-frags.
// Weights stream global->reg; k-loop fully unrolled, barrier-free.
// ---------------------------------------------------------------------------
template<int N, int K>
__device__ __forceinline__ void layer16(const __bf16* __restrict__ WT,
                                        const float* __restrict__ bias,
                                        const char* __restrict__ A, char* __restrict__ O,
                                        int wid, int lane) {
    constexpr int CG = N / 256;              // 16-col groups per wave
    const int l15 = lane & 15, lk = (lane >> 4) * 8;
    const int nb = wid * (N / 16);
    f32x4 acc[2][CG];
    #pragma unroll
    for (int i = 0; i < 2; ++i)
        #pragma unroll
        for (int c = 0; c < CG; ++c) acc[i][c] = (f32x4){0.f, 0.f, 0.f, 0.f};

    #pragma unroll
    for (int kt = 0; kt < K / 32; ++kt) {
        const int kk = kt * 32 + lk;
        bf16x8 a0 = rfragK(A, l15, kk);
        bf16x8 a1 = rfragK(A, 16 + l15, kk);
        #pragma unroll
        for (int c = 0; c < CG; ++c) {
            bf16x8 b = *reinterpret_cast<const bf16x8*>(WT + (size_t)(nb + c * 16 + l15) * K + kk);
            acc[0][c] = mfma16(a0, b, acc[0][c]);
            acc[1][c] = mfma16(a1, b, acc[1][c]);
        }
    }
    #pragma unroll
    for (int c = 0; c < CG; ++c) {
        const int col = nb + c * 16 + l15;
        const float bv = bias[col];
        #pragma unroll
        for (int i = 0; i < 2; ++i)
            #pragma unroll
            for (int r = 0; r < 4; ++r)
                wput(O, i * 16 + (lane >> 4) * 4 + r, col, tanh_fast(acc[i][c][r] + bv));
    }
}

// ---------------------------------------------------------------------------
// Fully fused, 256 blocks x 32 batch rows, 1024 threads (16 waves = 4/SIMD).
// LDS (80KB): Xs 8K | Xk 8K | state 8K | h1 32K | h2 16K | h3 8K.
// ---------------------------------------------------------------------------
__global__ __launch_bounds__(1024, 4) void fused_kernel(
    const float* __restrict__ z, const int* __restrict__ sid, const int* __restrict__ eid,
    const float* __restrict__ kp, const float* __restrict__ bstat, const float* __restrict__ bkdiff,
    const float* __restrict__ w_stat, const float* __restrict__ w_kdiff,
    const __bf16* __restrict__ KB, const __bf16* __restrict__ W1T,
    const __bf16* __restrict__ W2T, const __bf16* __restrict__ W3T,
    const float* __restrict__ b1, const float* __restrict__ b2, const float* __restrict__ b3,
    const float* __restrict__ W4, const float* __restrict__ b4,
    float* __restrict__ out) {
    __shared__ char lds[81920];
    char* Xs = lds;
    char* Xk = lds + 8192;
    char* st = lds + 16384;
    char* h1 = lds + 24576;
    char* h2 = lds + 57344;
    char* h3 = lds + 73728;

    const int t = threadIdx.x, lane = t & 63, wid = t >> 6;   // wid 0..15
    const int l15 = lane & 15, lk = (lane >> 4) * 8;
    const int wm = wid >> 3, wn = wid & 7;                    // 2 row x 8 col split
    const int rb0 = blockIdx.x * 32;
    const int colb = wn * 16 + l15;                           // phase-1/W3 column

    // ---- phase 0: gather Xs/Xk (all 1024 threads); prefetch KB/W1/kp to regs ----
    {
        int gr = t >> 4, row = gr & 31;          // 64 z-rows, 16 threads each
        bool ise = gr >= 32;
        int zrow = ise ? eid[rb0 + row] : sid[rb0 + row];
        const float* w = ise ? w_kdiff : w_stat;
        char* Xb = ise ? Xk : Xs;
        int c0 = (t & 15) * 8;                   // 8 elems per thread
        const float4* zp = reinterpret_cast<const float4*>(z + (size_t)zrow * DIM + c0);
        const float4* wp = reinterpret_cast<const float4*>(w + c0);
        float4 za = zp[0], zb = zp[1];
        float4 wa = wp[0], wb = wp[1];
        bf16x8 o;
        o[0] = (__bf16)(za.x * wa.x);  o[1] = (__bf16)(za.y * wa.y);
        o[2] = (__bf16)(za.z * wa.z);  o[3] = (__bf16)(za.w * wa.w);
        o[4] = (__bf16)(zb.x * wb.x);  o[5] = (__bf16)(zb.y * wb.y);
        o[6] = (__bf16)(zb.z * wb.z);  o[7] = (__bf16)(zb.w * wb.w);
        *reinterpret_cast<bf16x8*>(Xb + (c0 >> 6) * 4096 + swz(row, c0 & 63)) = o;
    }
    // KB b-frags for phase 1 (16 VGPR)
    bf16x8 kbf[4];
    #pragma unroll
    for (int kt = 0; kt < 4; ++kt)
        kbf[kt] = *reinterpret_cast<const bf16x8*>(KB + (size_t)colb * DIM + kt * 32 + lk);
    // W1 slice for layer 1 (8 frags = 32 VGPR) -> layer-1 k-loop is register-only
    bf16x8 w1f[4][2];
    #pragma unroll
    for (int kt = 0; kt < 4; ++kt)
        #pragma unroll
        for (int c = 0; c < 2; ++c)
            w1f[kt][c] = *reinterpret_cast<const bf16x8*>(
                W1T + (size_t)(wid * 32 + c * 16 + l15) * DIM + kt * 32 + lk);
    // kp values for phase-1 epilogue (8 VGPR)
    float kpv[4];
    #pragma unroll
    for (int r = 0; r < 4; ++r)
        kpv[r] = kp[(size_t)(rb0 + wm * 16 + (lane >> 4) * 4 + r) * KNOW_NUM + colb];
    __syncthreads();

    // ---- phase 1: dual GEMM (Xs,Xk)@KB^T + sigmoid-diff -> state ----
    {
        f32x4 aS = {0.f,0.f,0.f,0.f}, aK = {0.f,0.f,0.f,0.f};
        #pragma unroll
        for (int kt = 0; kt < 4; ++kt) {
            const int kk = kt * 32 + lk;
            bf16x8 s0 = rfragK(Xs, wm * 16 + l15, kk);
            bf16x8 q0 = rfragK(Xk, wm * 16 + l15, kk);
            aS = mfma16(s0, kbf[kt], aS);
            aK = mfma16(q0, kbf[kt], aK);
        }
        const float bs = bstat[0], bk = bkdiff[0];
        #pragma unroll
        for (int r = 0; r < 4; ++r) {
            float v = kpv[r] * (sigmoidf_(aS[r] + bs) - sigmoidf_(aK[r] + bk));
            wput(st, wm * 16 + (lane >> 4) * 4 + r, colb, v);
        }
    }
    __syncthreads();

    // ---- layer 1: h1 = tanh(state @ W1^T + b1), weights pre-loaded in regs ----
    {
        f32x4 acc[2][2];
        #pragma unroll
        for (int i = 0; i < 2; ++i)
            #pragma unroll
            for (int c = 0; c < 2; ++c) acc[i][c] = (f32x4){0.f,0.f,0.f,0.f};
        #pragma unroll
        for (int kt = 0; kt < 4; ++kt) {
            const int kk = kt * 32 + lk;
            bf16x8 a0 = rfragK(st, l15, kk);
            bf16x8 a1 = rfragK(st, 16 + l15, kk);
            #pragma unroll
            for (int c = 0; c < 2; ++c) {
                acc[0][c] = mfma16(a0, w1f[kt][c], acc[0][c]);
                acc[1][c] = mfma16(a1, w1f[kt][c], acc[1][c]);
            }
        }
        #pragma unroll
        for (int c = 0; c < 2; ++c) {
            const int col = wid * 32 + c * 16 + l15;
            const float bv = b1[col];
            #pragma unroll
            for (int i = 0; i < 2; ++i)
                #pragma unroll
                for (int r = 0; r < 4; ++r)
                    wput(h1, i * 16 + (lane >> 4) * 4 + r, col, tanh_fast(acc[i][c][r] + bv));
        }
    }
    __syncthreads();

    // ---- layer 2: h2 = tanh(h1 @ W2^T + b2), 16-way col split ----
    layer16<HIDDEN / 2, HIDDEN>(W2T, b2, h1, h2, wid, lane);
    __syncthreads();

    // ---- layer 3: h3 = tanh(h2 @ W3^T + b3), 8 col x 2 row split ----
    {
        f32x4 acc = {0.f,0.f,0.f,0.f};
        #pragma unroll
        for (int kt = 0; kt < 8; ++kt) {
            const int kk = kt * 32 + lk;
            bf16x8 a = rfragK(h2, wm * 16 + l15, kk);
            bf16x8 b = *reinterpret_cast<const bf16x8*>(
                W3T + (size_t)colb * (HIDDEN / 2) + kk);
            acc = mfma16(a, b, acc);
        }
        const float bv = b3[colb];
        #pragma unroll
        for (int r = 0; r < 4; ++r)
            wput(h3, wm * 16 + (lane >> 4) * 4 + r, colb, tanh_fast(acc[r] + bv));
    }
    __syncthreads();

    // ---- phase 5: out = sigmoid(dot(h3_row, W4) + b4), 16 lanes/row ----
    if (t < 512) {
        int row  = t >> 4;           // 0..31
        int part = (t & 15) * 8;     // 0..120
        bf16x8 h = rfragK(h3, row, part);
        float s = 0.f;
        #pragma unroll
        for (int j = 0; j < 8; ++j) s += (float)h[j] * W4[part + j];
        s += __shfl_xor(s, 1); s += __shfl_xor(s, 2);
        s += __shfl_xor(s, 4); s += __shfl_xor(s, 8);
        if ((t & 15) == 0) out[rb0 + row] = sigmoidf_(s + b4[0]);
    }
}

// ---------------------------------------------------------------------------
// prep: f32 -> bf16 weight reorg (unchanged).
// ---------------------------------------------------------------------------
__global__ void prep_kernel(const float* __restrict__ z,
                            const float* __restrict__ W1, const float* __restrict__ W2,
                            const float* __restrict__ W3,
                            __bf16* __restrict__ KB, __bf16* __restrict__ W1T,
                            __bf16* __restrict__ W2T, __bf16* __restrict__ W3T) {
    int i = blockIdx.x * 256 + threadIdx.x;
    if (i < 16384) { KB[i] = (__bf16)z[(size_t)(STU_NUM + PROB_NUM) * DIM + i]; return; }
    i -= 16384;
    if (i < 65536) {   // W1T [512][128] <- W1 [128][512]
        int n = i >> 7, k = i & 127;
        W1T[i] = (__bf16)W1[(size_t)k * HIDDEN + n]; return;
    }
    i -= 65536;
    if (i < 131072) {  // W2T [256][512] <- W2 [512][256]
        int n = i >> 9, k = i & 511;
        W2T[i] = (__bf16)W2[(size_t)k * (HIDDEN / 2) + n]; return;
    }
    i -= 131072;
    if (i < 32768) {   // W3T [128][256] <- W3 [256][128]
        int n = i >> 8, k = i & 255;
        W3T[i] = (__bf16)W3[(size_t)k * (HIDDEN / 4) + n];
    }
}

extern "C" void kernel_launch(void* const* d_in, const int* in_sizes, int n_in,
                              void* d_out, int out_size, void* d_ws, size_t ws_size,
                              hipStream_t stream) {
    const float* z       = (const float*)d_in[0];
    const int*   sid     = (const int*)d_in[1];
    const int*   eid     = (const int*)d_in[2];
    const float* kp      = (const float*)d_in[3];
    const float* w_stat  = (const float*)d_in[4];
    const float* b_stat  = (const float*)d_in[5];
    const float* w_kdiff = (const float*)d_in[6];
    const float* b_kdiff = (const float*)d_in[7];
    const float* W1      = (const float*)d_in[8];
    const float* b1      = (const float*)d_in[9];
    const float* W2      = (const float*)d_in[10];
    const float* b2      = (const float*)d_in[11];
    const float* W3      = (const float*)d_in[12];
    const float* b3      = (const float*)d_in[13];
    const float* W4      = (const float*)d_in[14];
    const float* b4      = (const float*)d_in[15];
    float* out = (float*)d_out;

    char* ws = (char*)d_ws;
    __bf16* KB  = (__bf16*)(ws + 0);        //  32 KB [128][128]
    __bf16* W1T = (__bf16*)(ws + 32768);    // 128 KB [512][128]
    __bf16* W2T = (__bf16*)(ws + 163840);   // 256 KB [256][512]
    __bf16* W3T = (__bf16*)(ws + 425984);   //  64 KB [128][256]

    hipLaunchKernelGGL(prep_kernel, dim3(960), dim3(256), 0, stream,
                       z, W1, W2, W3, KB, W1T, W2T, W3T);

    hipLaunchKernelGGL(fused_kernel, dim3(BATCH / 32), dim3(1024), 0, stream,
                       z, sid, eid, kp, b_stat, b_kdiff, w_stat, w_kdiff,
                       KB, W1T, W2T, W3T, b1, b2, b3, W4, b4, out);
}